// Round 1
// baseline (2845.506 us; speedup 1.0000x reference)
//
#include <hip/hip_runtime.h>
#include <hip/hip_bf16.h>
#include <math.h>

#define BM 64
#define BN 64
#define BK 16
#define LDS_PAD 68   // 16B-aligned padded row (68*4=272B, multiple of 16)

// ---------------------------------------------------------------------------
// GEMM 1: [8192,1024] x [1024,3072] -> Q/K/V in [b*16+h][n][64] layout
// ---------------------------------------------------------------------------
__global__ __launch_bounds__(256) void gemm_qkv(
    const float* __restrict__ x,
    const float* __restrict__ Wq,
    const float* __restrict__ Wkv,
    float* __restrict__ Qb,
    float* __restrict__ Kb,
    float* __restrict__ Vb)
{
    __shared__ float As[BK][LDS_PAD];
    __shared__ float Bs[BK][LDS_PAD];

    const int tid = threadIdx.x;
    const int tx = tid & 15;        // 0..15 -> output col group
    const int ty = tid >> 4;        // 0..15 -> output row group
    const int rowBase = blockIdx.y * BM;
    const int colBase = blockIdx.x * BN;

    const float* Wp; int ldw; int cadj;
    if (colBase < 1024)      { Wp = Wq;  ldw = 1024; cadj = colBase; }
    else                     { Wp = Wkv; ldw = 2048; cadj = colBase - 1024; }

    // staging index maps
    const int ar = tid >> 2;          // 0..63 tile row (A)
    const int ak = (tid & 3) << 2;    // 0,4,8,12 k offset (A)
    const int bk = tid >> 4;          // 0..15 k row (B)
    const int bc = (tid & 15) << 2;   // 0..60 col offset (B)

    float acc[4][4];
    #pragma unroll
    for (int i = 0; i < 4; ++i)
        #pragma unroll
        for (int j = 0; j < 4; ++j) acc[i][j] = 0.f;

    for (int k0 = 0; k0 < 1024; k0 += BK) {
        float4 av = *(const float4*)(x + (size_t)(rowBase + ar) * 1024 + k0 + ak);
        float4 bv = *(const float4*)(Wp + (size_t)(k0 + bk) * ldw + cadj + bc);
        __syncthreads();
        As[ak + 0][ar] = av.x;
        As[ak + 1][ar] = av.y;
        As[ak + 2][ar] = av.z;
        As[ak + 3][ar] = av.w;
        *(float4*)&Bs[bk][bc] = bv;
        __syncthreads();
        #pragma unroll
        for (int kk = 0; kk < BK; ++kk) {
            float4 a = *(const float4*)&As[kk][ty << 2];
            float4 b = *(const float4*)&Bs[kk][tx << 2];
            float af[4] = {a.x, a.y, a.z, a.w};
            float bf[4] = {b.x, b.y, b.z, b.w};
            #pragma unroll
            for (int i = 0; i < 4; ++i)
                #pragma unroll
                for (int j = 0; j < 4; ++j)
                    acc[i][j] += af[i] * bf[j];
        }
    }

    // epilogue: scatter to Q/K/V head-split layout
    const int seg = colBase >> 10;          // 0=Q 1=K 2=V
    float* dst = (seg == 0) ? Qb : ((seg == 1) ? Kb : Vb);
    const int ccBase = (colBase & 1023) + (tx << 2);  // col within segment
    const int h = ccBase >> 6;
    const int d = ccBase & 63;
    #pragma unroll
    for (int i = 0; i < 4; ++i) {
        int r = rowBase + (ty << 2) + i;
        int b = r >> 11;          // /2048
        int n = r & 2047;
        float4 v = {acc[i][0], acc[i][1], acc[i][2], acc[i][3]};
        *(float4*)(dst + ((((size_t)b * 16 + h) * 2048 + n) << 6) + d) = v;
    }
}

// ---------------------------------------------------------------------------
// Flash attention (causal, online softmax). 1 thread = 1 query row.
// Block = 256 threads = 256 query rows of one (b,h). K/V tiles in LDS.
// ---------------------------------------------------------------------------
__global__ __launch_bounds__(256) void flash_attn(
    const float* __restrict__ Qb,
    const float* __restrict__ Kb,
    const float* __restrict__ Vb,
    float* __restrict__ Ob)
{
    __shared__ float Ks[64][64];
    __shared__ float Vs[64][64];

    const int tid = threadIdx.x;
    const int qblk = blockIdx.x & 7;       // 2048/256 = 8 q-slabs
    const int bh = blockIdx.x >> 3;        // 0..63
    const int i = (qblk << 8) + tid;       // query index 0..2047

    const float* qptr = Qb + ((size_t)bh * 2048 + i) * 64;
    float q[64], o[64];
    #pragma unroll
    for (int d = 0; d < 64; d += 4) {
        float4 t = *(const float4*)(qptr + d);
        q[d] = t.x; q[d+1] = t.y; q[d+2] = t.z; q[d+3] = t.w;
    }
    #pragma unroll
    for (int d = 0; d < 64; ++d) o[d] = 0.f;

    float m = -INFINITY, l = 0.f;

    const int lastTile = ((qblk << 8) + 255) >> 6;   // uniform per block
    for (int jt = 0; jt <= lastTile; ++jt) {
        const float* kp = Kb + ((size_t)bh * 2048 + (jt << 6)) * 64;
        const float* vp = Vb + ((size_t)bh * 2048 + (jt << 6)) * 64;
        __syncthreads();
        #pragma unroll
        for (int s = 0; s < 4; ++s) {
            int p = tid + (s << 8);        // 0..1023 float4 units
            int row = p >> 4;
            int c = (p & 15) << 2;
            *(float4*)&Ks[row][c] = *(const float4*)(kp + row * 64 + c);
            *(float4*)&Vs[row][c] = *(const float4*)(vp + row * 64 + c);
        }
        __syncthreads();

        int jlim = i - (jt << 6) + 1;      // causal: keys j with jt*64+j <= i
        if (jlim > 64) jlim = 64;
        for (int j = 0; j < jlim; ++j) {
            float s = 0.f;
            #pragma unroll
            for (int d = 0; d < 64; d += 4) {
                float4 kv4 = *(const float4*)&Ks[j][d];
                s += q[d] * kv4.x + q[d+1] * kv4.y + q[d+2] * kv4.z + q[d+3] * kv4.w;
            }
            s *= 0.125f;                    // 1/sqrt(64)
            float mnew = fmaxf(m, s);
            float corr = __expf(m - mnew);
            float p = __expf(s - mnew);
            l = l * corr + p;
            m = mnew;
            #pragma unroll
            for (int d = 0; d < 64; d += 4) {
                float4 vv = *(const float4*)&Vs[j][d];
                o[d]   = o[d]   * corr + p * vv.x;
                o[d+1] = o[d+1] * corr + p * vv.y;
                o[d+2] = o[d+2] * corr + p * vv.z;
                o[d+3] = o[d+3] * corr + p * vv.w;
            }
        }
    }

    float inv = 1.f / l;
    const int b = bh >> 4, h = bh & 15;
    float* op = Ob + ((size_t)(b * 2048 + i)) * 1024 + h * 64;
    #pragma unroll
    for (int d = 0; d < 64; d += 4) {
        float4 t = {o[d] * inv, o[d+1] * inv, o[d+2] * inv, o[d+3] * inv};
        *(float4*)(op + d) = t;
    }
}

// ---------------------------------------------------------------------------
// GEMM 2: [8192,1024] x [1024,1024] + bias -> out
// ---------------------------------------------------------------------------
__global__ __launch_bounds__(256) void gemm_out(
    const float* __restrict__ O,
    const float* __restrict__ Wo,
    const float* __restrict__ bo,
    float* __restrict__ out)
{
    __shared__ float As[BK][LDS_PAD];
    __shared__ float Bs[BK][LDS_PAD];

    const int tid = threadIdx.x;
    const int tx = tid & 15;
    const int ty = tid >> 4;
    const int rowBase = blockIdx.y * BM;
    const int colBase = blockIdx.x * BN;

    const int ar = tid >> 2;
    const int ak = (tid & 3) << 2;
    const int bk = tid >> 4;
    const int bc = (tid & 15) << 2;

    float acc[4][4];
    #pragma unroll
    for (int i = 0; i < 4; ++i)
        #pragma unroll
        for (int j = 0; j < 4; ++j) acc[i][j] = 0.f;

    for (int k0 = 0; k0 < 1024; k0 += BK) {
        float4 av = *(const float4*)(O + (size_t)(rowBase + ar) * 1024 + k0 + ak);
        float4 bv = *(const float4*)(Wo + (size_t)(k0 + bk) * 1024 + colBase + bc);
        __syncthreads();
        As[ak + 0][ar] = av.x;
        As[ak + 1][ar] = av.y;
        As[ak + 2][ar] = av.z;
        As[ak + 3][ar] = av.w;
        *(float4*)&Bs[bk][bc] = bv;
        __syncthreads();
        #pragma unroll
        for (int kk = 0; kk < BK; ++kk) {
            float4 a = *(const float4*)&As[kk][ty << 2];
            float4 b = *(const float4*)&Bs[kk][tx << 2];
            float af[4] = {a.x, a.y, a.z, a.w};
            float bf[4] = {b.x, b.y, b.z, b.w};
            #pragma unroll
            for (int i = 0; i < 4; ++i)
                #pragma unroll
                for (int j = 0; j < 4; ++j)
                    acc[i][j] += af[i] * bf[j];
        }
    }

    float4 bias = *(const float4*)(bo + colBase + (tx << 2));
    float bf[4] = {bias.x, bias.y, bias.z, bias.w};
    #pragma unroll
    for (int i = 0; i < 4; ++i) {
        int r = rowBase + (ty << 2) + i;
        float4 v = {acc[i][0] + bf[0], acc[i][1] + bf[1],
                    acc[i][2] + bf[2], acc[i][3] + bf[3]};
        *(float4*)(out + (size_t)r * 1024 + colBase + (tx << 2)) = v;
    }
}

// ---------------------------------------------------------------------------
extern "C" void kernel_launch(void* const* d_in, const int* in_sizes, int n_in,
                              void* d_out, int out_size, void* d_ws, size_t ws_size,
                              hipStream_t stream) {
    const float* x   = (const float*)d_in[0];   // [4,2048,1024]
    const float* Wq  = (const float*)d_in[1];   // [1024,1024]
    const float* Wkv = (const float*)d_in[2];   // [1024,2048]
    const float* Wo  = (const float*)d_in[3];   // [1024,1024]
    const float* bo  = (const float*)d_in[4];   // [1024]
    float* out = (float*)d_out;                 // [4,2048,1024]

    const size_t QKV_ELEMS = (size_t)4 * 16 * 2048 * 64;  // 8388608
    float* Qb = (float*)d_ws;
    float* Kb = Qb + QKV_ELEMS;
    float* Vb = Kb + QKV_ELEMS;
    float* Ob = Vb + QKV_ELEMS;   // [4*2048, 1024]

    // 1) QKV projection: 8192 x 3072
    gemm_qkv<<<dim3(3072 / BN, 8192 / BM), 256, 0, stream>>>(x, Wq, Wkv, Qb, Kb, Vb);

    // 2) causal flash attention: 64 bh-pairs x 8 q-slabs
    flash_attn<<<dim3(64 * 8), 256, 0, stream>>>(Qb, Kb, Vb, Ob);

    // 3) output projection + bias
    gemm_out<<<dim3(1024 / BN, 8192 / BM), 256, 0, stream>>>(Ob, Wo, bo, out);
}

// Round 2
// 1379.592 us; speedup vs baseline: 2.0626x; 2.0626x over previous
//
#include <hip/hip_runtime.h>
#include <hip/hip_bf16.h>
#include <math.h>

#define BM 64
#define BN 64
#define BK 16
#define LDS_PAD 68

typedef __attribute__((ext_vector_type(8))) short bf16x8;
typedef __attribute__((ext_vector_type(4))) float f32x4;

static __device__ inline ushort f2bf(float f) {
    union { float f; unsigned u; } v; v.f = f;
    unsigned r = (v.u + 0x7fff + ((v.u >> 16) & 1)) >> 16;   // RNE
    return (ushort)r;
}

// ---------------------------------------------------------------------------
// GEMM 1 (fp32 compute): x[8192,1024] x [Wq|Wkv] -> bf16 Q/K/V, head-split
// Q,K,V layout: [b*16+h][n][64]
// ---------------------------------------------------------------------------
__global__ __launch_bounds__(256) void gemm_qkv(
    const float* __restrict__ x,
    const float* __restrict__ Wq,
    const float* __restrict__ Wkv,
    ushort* __restrict__ Qb,
    ushort* __restrict__ Kb,
    ushort* __restrict__ Vb)
{
    __shared__ float As[BK][LDS_PAD];
    __shared__ float Bs[BK][LDS_PAD];

    const int tid = threadIdx.x;
    const int tx = tid & 15;
    const int ty = tid >> 4;
    const int rowBase = blockIdx.y * BM;
    const int colBase = blockIdx.x * BN;

    const float* Wp; int ldw; int cadj;
    if (colBase < 1024) { Wp = Wq;  ldw = 1024; cadj = colBase; }
    else                { Wp = Wkv; ldw = 2048; cadj = colBase - 1024; }

    const int ar = tid >> 2;
    const int ak = (tid & 3) << 2;
    const int bk = tid >> 4;
    const int bc = (tid & 15) << 2;

    float acc[4][4];
    #pragma unroll
    for (int i = 0; i < 4; ++i)
        #pragma unroll
        for (int j = 0; j < 4; ++j) acc[i][j] = 0.f;

    for (int k0 = 0; k0 < 1024; k0 += BK) {
        float4 av = *(const float4*)(x + (size_t)(rowBase + ar) * 1024 + k0 + ak);
        float4 bv = *(const float4*)(Wp + (size_t)(k0 + bk) * ldw + cadj + bc);
        __syncthreads();
        As[ak + 0][ar] = av.x;
        As[ak + 1][ar] = av.y;
        As[ak + 2][ar] = av.z;
        As[ak + 3][ar] = av.w;
        *(float4*)&Bs[bk][bc] = bv;
        __syncthreads();
        #pragma unroll
        for (int kk = 0; kk < BK; ++kk) {
            float4 a = *(const float4*)&As[kk][ty << 2];
            float4 b = *(const float4*)&Bs[kk][tx << 2];
            float af[4] = {a.x, a.y, a.z, a.w};
            float bf[4] = {b.x, b.y, b.z, b.w};
            #pragma unroll
            for (int i = 0; i < 4; ++i)
                #pragma unroll
                for (int j = 0; j < 4; ++j)
                    acc[i][j] += af[i] * bf[j];
        }
    }

    const int seg = colBase >> 10;          // 0=Q 1=K 2=V
    ushort* dst = (seg == 0) ? Qb : ((seg == 1) ? Kb : Vb);
    const int ccBase = (colBase & 1023) + (tx << 2);
    const int h = ccBase >> 6;
    const int d = ccBase & 63;
    #pragma unroll
    for (int i = 0; i < 4; ++i) {
        int r = rowBase + (ty << 2) + i;
        int b = r >> 11;
        int n = r & 2047;
        ushort4 v4;
        v4.x = f2bf(acc[i][0]); v4.y = f2bf(acc[i][1]);
        v4.z = f2bf(acc[i][2]); v4.w = f2bf(acc[i][3]);
        *(ushort4*)(dst + ((((size_t)b * 16 + h) * 2048 + n) << 6) + d) = v4;
    }
}

// ---------------------------------------------------------------------------
// V transpose: Vb[bh][n][64] -> Vt[bh][64][2048]  (register transpose, no LDS)
// One wave per 64x64 tile: lane = d column, loop = key row.
// ---------------------------------------------------------------------------
__global__ __launch_bounds__(256) void transpose_v(
    const ushort* __restrict__ Vb,
    ushort* __restrict__ Vt)
{
    const int w = threadIdx.x >> 6;
    const int lane = threadIdx.x & 63;
    const int tile = blockIdx.x * 4 + w;        // 2048 tiles total
    const int bh = tile >> 5;
    const int kb = (tile & 31) << 6;

    const ushort* src = Vb + ((size_t)bh * 2048 + kb) * 64 + lane;
    ushort v[64];
    #pragma unroll
    for (int k = 0; k < 64; ++k)
        v[k] = src[(size_t)k * 64];             // coalesced: lanes = consecutive d

    ushort* dst = Vt + ((size_t)bh * 64 + lane) * 2048 + kb;
    #pragma unroll
    for (int k = 0; k < 64; k += 8) {
        bf16x8 t;
        #pragma unroll
        for (int j = 0; j < 8; ++j) t[j] = (short)v[k + j];
        *(bf16x8*)(dst + k) = t;                // coalesced 16B stores
    }
}

// ---------------------------------------------------------------------------
// MFMA flash attention (causal). 1 wave = 16 q-rows, 4 independent waves/block.
// Q,K: [bh][n][64] bf16 ; Vt: [bh][64][2048] bf16 ; O: [b][n][1024] fp32
// ---------------------------------------------------------------------------
__global__ __launch_bounds__(256) void flash_mfma(
    const ushort* __restrict__ Qb,
    const ushort* __restrict__ Kb,
    const ushort* __restrict__ Vt,
    float* __restrict__ Ob)
{
    __shared__ ushort Ps[4][16][80];   // per-wave P tile, padded stride 80

    const int tid = threadIdx.x;
    const int w = tid >> 6;
    const int lane = tid & 63;
    const int l15 = lane & 15;
    const int quad = lane >> 4;

    const int qt = blockIdx.x;          // q-tile (64 rows)
    const int bh = blockIdx.y;          // 0..63
    const int q0 = qt << 6;

    // Q fragments (A-operand): row m = l15, k = quad*8 + j (+32 for chunk 1)
    const ushort* qptr = Qb + ((size_t)bh * 2048 + q0 + w * 16 + l15) * 64 + quad * 8;
    bf16x8 qf0 = *(const bf16x8*)qptr;
    bf16x8 qf1 = *(const bf16x8*)(qptr + 32);

    float m_r[4], l_r[4];
    f32x4 o[4];
    #pragma unroll
    for (int r = 0; r < 4; ++r) { m_r[r] = -INFINITY; l_r[r] = 0.f; }
    #pragma unroll
    for (int nb = 0; nb < 4; ++nb) o[nb] = (f32x4){0.f, 0.f, 0.f, 0.f};

    const int qb = qt;   // diagonal tile index
    for (int jt = 0; jt <= qb; ++jt) {
        const bool diag = (jt == qb);

        // ---- S = Q K^T (16 x 64) ----
        f32x4 S[4];
        const ushort* kbase = Kb + ((size_t)bh * 2048 + (jt << 6)) * 64;
        #pragma unroll
        for (int cb = 0; cb < 4; ++cb) {
            const ushort* kp = kbase + (size_t)(cb * 16 + l15) * 64 + quad * 8;
            bf16x8 kf0 = *(const bf16x8*)kp;
            bf16x8 kf1 = *(const bf16x8*)(kp + 32);
            f32x4 s = (f32x4){0.f, 0.f, 0.f, 0.f};
            s = __builtin_amdgcn_mfma_f32_16x16x32_bf16(qf0, kf0, s, 0, 0, 0);
            s = __builtin_amdgcn_mfma_f32_16x16x32_bf16(qf1, kf1, s, 0, 0, 0);
            S[cb] = s;
        }

        // ---- scale + causal mask ----
        #pragma unroll
        for (int cb = 0; cb < 4; ++cb) {
            const int jg = (jt << 6) + cb * 16 + l15;
            #pragma unroll
            for (int r = 0; r < 4; ++r) {
                float s = S[cb][r] * 0.125f;
                const int ig = q0 + w * 16 + quad * 4 + r;
                if (diag && jg > ig) s = -INFINITY;
                S[cb][r] = s;
            }
        }

        // ---- online softmax (per row r, reduce over 16 lanes) ----
        float corr[4];
        #pragma unroll
        for (int r = 0; r < 4; ++r) {
            float mx = fmaxf(fmaxf(S[0][r], S[1][r]), fmaxf(S[2][r], S[3][r]));
            mx = fmaxf(mx, __shfl_xor(mx, 1));
            mx = fmaxf(mx, __shfl_xor(mx, 2));
            mx = fmaxf(mx, __shfl_xor(mx, 4));
            mx = fmaxf(mx, __shfl_xor(mx, 8));
            const float mnew = fmaxf(m_r[r], mx);
            corr[r] = __expf(m_r[r] - mnew);
            float rs = 0.f;
            #pragma unroll
            for (int cb = 0; cb < 4; ++cb) {
                float p = __expf(S[cb][r] - mnew);
                S[cb][r] = p;
                rs += p;
            }
            rs += __shfl_xor(rs, 1);
            rs += __shfl_xor(rs, 2);
            rs += __shfl_xor(rs, 4);
            rs += __shfl_xor(rs, 8);
            l_r[r] = l_r[r] * corr[r] + rs;
            m_r[r] = mnew;
        }

        // ---- P -> LDS (bf16), rescale O ----
        #pragma unroll
        for (int cb = 0; cb < 4; ++cb)
            #pragma unroll
            for (int r = 0; r < 4; ++r)
                Ps[w][quad * 4 + r][cb * 16 + l15] = f2bf(S[cb][r]);
        #pragma unroll
        for (int nb = 0; nb < 4; ++nb)
            #pragma unroll
            for (int r = 0; r < 4; ++r)
                o[nb][r] *= corr[r];

        // ---- O += P V ----  (A = P from LDS, B = Vt rows from global)
        bf16x8 pf0 = *(const bf16x8*)&Ps[w][l15][quad * 8];
        bf16x8 pf1 = *(const bf16x8*)&Ps[w][l15][32 + quad * 8];
        const ushort* vtb = Vt + (size_t)bh * 64 * 2048 + (jt << 6);
        #pragma unroll
        for (int nb = 0; nb < 4; ++nb) {
            const ushort* vp = vtb + (size_t)(nb * 16 + l15) * 2048 + quad * 8;
            bf16x8 vf0 = *(const bf16x8*)vp;
            bf16x8 vf1 = *(const bf16x8*)(vp + 32);
            o[nb] = __builtin_amdgcn_mfma_f32_16x16x32_bf16(pf0, vf0, o[nb], 0, 0, 0);
            o[nb] = __builtin_amdgcn_mfma_f32_16x16x32_bf16(pf1, vf1, o[nb], 0, 0, 0);
        }
    }

    // ---- normalize + store O in [b][n][h*64] fp32 ----
    const int b = bh >> 4, h = bh & 15;
    #pragma unroll
    for (int r = 0; r < 4; ++r) {
        const int ig = q0 + w * 16 + quad * 4 + r;
        const float inv = 1.f / l_r[r];
        float* op = Ob + ((size_t)b * 2048 + ig) * 1024 + h * 64 + l15;
        #pragma unroll
        for (int nb = 0; nb < 4; ++nb)
            op[nb * 16] = o[nb][r] * inv;
    }
}

// ---------------------------------------------------------------------------
// GEMM 2 (fp32): O[8192,1024] x Wo[1024,1024] + bo -> out
// ---------------------------------------------------------------------------
__global__ __launch_bounds__(256) void gemm_out(
    const float* __restrict__ O,
    const float* __restrict__ Wo,
    const float* __restrict__ bo,
    float* __restrict__ out)
{
    __shared__ float As[BK][LDS_PAD];
    __shared__ float Bs[BK][LDS_PAD];

    const int tid = threadIdx.x;
    const int tx = tid & 15;
    const int ty = tid >> 4;
    const int rowBase = blockIdx.y * BM;
    const int colBase = blockIdx.x * BN;

    const int ar = tid >> 2;
    const int ak = (tid & 3) << 2;
    const int bk = tid >> 4;
    const int bc = (tid & 15) << 2;

    float acc[4][4];
    #pragma unroll
    for (int i = 0; i < 4; ++i)
        #pragma unroll
        for (int j = 0; j < 4; ++j) acc[i][j] = 0.f;

    for (int k0 = 0; k0 < 1024; k0 += BK) {
        float4 av = *(const float4*)(O + (size_t)(rowBase + ar) * 1024 + k0 + ak);
        float4 bv = *(const float4*)(Wo + (size_t)(k0 + bk) * 1024 + colBase + bc);
        __syncthreads();
        As[ak + 0][ar] = av.x;
        As[ak + 1][ar] = av.y;
        As[ak + 2][ar] = av.z;
        As[ak + 3][ar] = av.w;
        *(float4*)&Bs[bk][bc] = bv;
        __syncthreads();
        #pragma unroll
        for (int kk = 0; kk < BK; ++kk) {
            float4 a = *(const float4*)&As[kk][ty << 2];
            float4 b = *(const float4*)&Bs[kk][tx << 2];
            float af[4] = {a.x, a.y, a.z, a.w};
            float bf[4] = {b.x, b.y, b.z, b.w};
            #pragma unroll
            for (int i = 0; i < 4; ++i)
                #pragma unroll
                for (int j = 0; j < 4; ++j)
                    acc[i][j] += af[i] * bf[j];
        }
    }

    float4 bias = *(const float4*)(bo + colBase + (tx << 2));
    float bf[4] = {bias.x, bias.y, bias.z, bias.w};
    #pragma unroll
    for (int i = 0; i < 4; ++i) {
        int r = rowBase + (ty << 2) + i;
        float4 v = {acc[i][0] + bf[0], acc[i][1] + bf[1],
                    acc[i][2] + bf[2], acc[i][3] + bf[3]};
        *(float4*)(out + (size_t)r * 1024 + colBase + (tx << 2)) = v;
    }
}

// ---------------------------------------------------------------------------
extern "C" void kernel_launch(void* const* d_in, const int* in_sizes, int n_in,
                              void* d_out, int out_size, void* d_ws, size_t ws_size,
                              hipStream_t stream) {
    const float* x   = (const float*)d_in[0];
    const float* Wq  = (const float*)d_in[1];
    const float* Wkv = (const float*)d_in[2];
    const float* Wo  = (const float*)d_in[3];
    const float* bo  = (const float*)d_in[4];
    float* out = (float*)d_out;

    const size_t QKV = (size_t)4 * 16 * 2048 * 64;      // 8388608 elements
    char* ws = (char*)d_ws;
    ushort* Qb = (ushort*)(ws);                         // 16 MB
    ushort* Kb = (ushort*)(ws + QKV * 2);               // 16 MB
    ushort* Vb = (ushort*)(ws + QKV * 4);               // 16 MB
    ushort* Vt = (ushort*)(ws + QKV * 6);               // 16 MB
    float*  Ob = (float*) (ws + QKV * 8);               // 32 MB

    gemm_qkv<<<dim3(3072 / BN, 8192 / BM), 256, 0, stream>>>(x, Wq, Wkv, Qb, Kb, Vb);
    transpose_v<<<dim3(512), 256, 0, stream>>>(Vb, Vt);
    flash_mfma<<<dim3(32, 64), 256, 0, stream>>>(Qb, Kb, Vt, Ob);
    gemm_out<<<dim3(1024 / BN, 8192 / BM), 256, 0, stream>>>(Ob, Wo, bo, out);
}

// Round 3
// 640.725 us; speedup vs baseline: 4.4411x; 2.1532x over previous
//
#include <hip/hip_runtime.h>
#include <hip/hip_bf16.h>
#include <math.h>

typedef __attribute__((ext_vector_type(8))) short bf16x8;
typedef __attribute__((ext_vector_type(4))) float f32x4;

static __device__ inline ushort f2bf(float f) {
    union { float f; unsigned u; } v; v.f = f;
    unsigned r = (v.u + 0x7fff + ((v.u >> 16) & 1)) >> 16;   // RNE
    return (ushort)r;
}

#define GLD_LDS(g, l) \
    __builtin_amdgcn_global_load_lds( \
        (const __attribute__((address_space(1))) void*)(g), \
        (__attribute__((address_space(3))) void*)(l), 16, 0, 0)

// ---------------------------------------------------------------------------
// x fp32 -> bf16  (8388608 elems, 8 per thread)
// ---------------------------------------------------------------------------
__global__ __launch_bounds__(256) void convert_x(
    const float* __restrict__ x, ushort* __restrict__ xb)
{
    const size_t i = ((size_t)blockIdx.x * 256 + threadIdx.x) * 8;
    float4 a = *(const float4*)(x + i);
    float4 b = *(const float4*)(x + i + 4);
    bf16x8 t;
    t[0] = (short)f2bf(a.x); t[1] = (short)f2bf(a.y);
    t[2] = (short)f2bf(a.z); t[3] = (short)f2bf(a.w);
    t[4] = (short)f2bf(b.x); t[5] = (short)f2bf(b.y);
    t[6] = (short)f2bf(b.z); t[7] = (short)f2bf(b.w);
    *(bf16x8*)(xb + i) = t;
}

// ---------------------------------------------------------------------------
// Weights fp32 [K][N] -> Wt bf16 [N_total=4096][K=1024] (transposed, fused cast)
// rows 0-1023: Wq ; 1024-3071: Wkv ; 3072-4095: Wo.  1 wave per 64x64 tile.
// ---------------------------------------------------------------------------
__global__ __launch_bounds__(256) void prep_w(
    const float* __restrict__ Wq, const float* __restrict__ Wkv,
    const float* __restrict__ Wo, ushort* __restrict__ Wt)
{
    const int w = threadIdx.x >> 6;
    const int lane = threadIdx.x & 63;
    const int tile = blockIdx.x * 4 + w;       // 0..1023
    const int r0 = (tile >> 4) << 6;           // output row (source col) base
    const int k0 = (tile & 15) << 6;           // k base

    const float* src; int ld, c0;
    if (r0 < 1024)      { src = Wq;  ld = 1024; c0 = r0; }
    else if (r0 < 3072) { src = Wkv; ld = 2048; c0 = r0 - 1024; }
    else                { src = Wo;  ld = 1024; c0 = r0 - 3072; }

    ushort v[64];
    #pragma unroll
    for (int k = 0; k < 64; ++k)
        v[k] = f2bf(src[(size_t)(k0 + k) * ld + c0 + lane]);   // coalesced reads

    ushort* dst = Wt + (size_t)(r0 + lane) * 1024 + k0;
    #pragma unroll
    for (int k = 0; k < 64; k += 8) {
        bf16x8 t;
        #pragma unroll
        for (int j = 0; j < 8; ++j) t[j] = (short)v[k + j];
        *(bf16x8*)(dst + k) = t;
    }
}

// ---------------------------------------------------------------------------
// m97-style bf16 MFMA GEMM main loop (128x128 tile, BK=32), shared by both
// projection kernels via macro. A:[M][1024] bf16, Bt:[N][1024] bf16.
// ---------------------------------------------------------------------------
#define GEMM_MAIN_LOOP(Aptr, Btptr)                                            \
    __shared__ ushort As[128 * 32];                                            \
    __shared__ ushort Bs[128 * 32];                                            \
    const int tid = threadIdx.x;                                               \
    const int lane = tid & 63;                                                 \
    const int w = tid >> 6;                                                    \
    const int l15 = lane & 15;                                                 \
    const int quad = lane >> 4;                                                \
    const int wm = w & 1, wn = w >> 1;                                         \
    const int rowBase = blockIdx.y * 128;                                      \
    const int colBase = blockIdx.x * 128;                                      \
    const int sRow = lane >> 2;                                                \
    const int sOff = (lane & 3) * 8;                                           \
    const ushort* aG0 = (Aptr) + (size_t)(rowBase + (w*2+0)*16 + sRow) * 1024 + sOff; \
    const ushort* aG1 = (Aptr) + (size_t)(rowBase + (w*2+1)*16 + sRow) * 1024 + sOff; \
    const ushort* bG0 = (Btptr) + (size_t)(colBase + (w*2+0)*16 + sRow) * 1024 + sOff; \
    const ushort* bG1 = (Btptr) + (size_t)(colBase + (w*2+1)*16 + sRow) * 1024 + sOff; \
    ushort* aL0 = As + (w*2+0)*512;                                            \
    ushort* aL1 = As + (w*2+1)*512;                                            \
    ushort* bL0 = Bs + (w*2+0)*512;                                            \
    ushort* bL1 = Bs + (w*2+1)*512;                                            \
    f32x4 acc[4][4];                                                           \
    _Pragma("unroll")                                                          \
    for (int i = 0; i < 4; ++i)                                                \
        _Pragma("unroll")                                                      \
        for (int j = 0; j < 4; ++j) acc[i][j] = (f32x4){0.f,0.f,0.f,0.f};      \
    for (int k0 = 0; k0 < 1024; k0 += 32) {                                    \
        __syncthreads();                                                       \
        GLD_LDS(aG0 + k0, aL0);                                                \
        GLD_LDS(aG1 + k0, aL1);                                                \
        GLD_LDS(bG0 + k0, bL0);                                                \
        GLD_LDS(bG1 + k0, bL1);                                                \
        __syncthreads();                                                       \
        bf16x8 af[4], bf[4];                                                   \
        _Pragma("unroll")                                                      \
        for (int mi = 0; mi < 4; ++mi)                                         \
            af[mi] = *(const bf16x8*)&As[(wm*64 + mi*16 + l15)*32 + quad*8];   \
        _Pragma("unroll")                                                      \
        for (int ni = 0; ni < 4; ++ni)                                         \
            bf[ni] = *(const bf16x8*)&Bs[(wn*64 + ni*16 + l15)*32 + quad*8];   \
        _Pragma("unroll")                                                      \
        for (int mi = 0; mi < 4; ++mi)                                         \
            _Pragma("unroll")                                                  \
            for (int ni = 0; ni < 4; ++ni)                                     \
                acc[mi][ni] = __builtin_amdgcn_mfma_f32_16x16x32_bf16(         \
                    af[mi], bf[ni], acc[mi][ni], 0, 0, 0);                     \
    }

// ---------------------------------------------------------------------------
// GEMM 1: xb[8192,1024] x Wt[0:3072] -> bf16 Q/K/V in [b*16+h][n][64]
// ---------------------------------------------------------------------------
__global__ __launch_bounds__(256) void gemm_qkv(
    const ushort* __restrict__ A, const ushort* __restrict__ Bt,
    ushort* __restrict__ Qb, ushort* __restrict__ Kb, ushort* __restrict__ Vb)
{
    GEMM_MAIN_LOOP(A, Bt)

    const int seg = colBase >> 10;          // 0=Q 1=K 2=V (128 | 1024)
    ushort* dst = (seg == 0) ? Qb : ((seg == 1) ? Kb : Vb);
    #pragma unroll
    for (int mi = 0; mi < 4; ++mi) {
        #pragma unroll
        for (int ni = 0; ni < 4; ++ni) {
            const int n = colBase + wn*64 + ni*16 + l15;
            const int c = n & 1023;
            const int h = c >> 6, d = c & 63;
            #pragma unroll
            for (int r = 0; r < 4; ++r) {
                const int m = rowBase + wm*64 + mi*16 + quad*4 + r;
                const int b = m >> 11, nn = m & 2047;
                dst[((((size_t)b*16 + h)*2048 + nn) << 6) + d] = f2bf(acc[mi][ni][r]);
            }
        }
    }
}

// ---------------------------------------------------------------------------
// GEMM 2: Ob[8192,1024] x Wt[3072:4096] + bo -> fp32 out [8192,1024]
// ---------------------------------------------------------------------------
__global__ __launch_bounds__(256) void gemm_out(
    const ushort* __restrict__ A, const ushort* __restrict__ Bt,
    const float* __restrict__ bo, float* __restrict__ out)
{
    GEMM_MAIN_LOOP(A, Bt)

    #pragma unroll
    for (int mi = 0; mi < 4; ++mi) {
        #pragma unroll
        for (int ni = 0; ni < 4; ++ni) {
            const int n = colBase + wn*64 + ni*16 + l15;
            const float bb = bo[n];
            #pragma unroll
            for (int r = 0; r < 4; ++r) {
                const int m = rowBase + wm*64 + mi*16 + quad*4 + r;
                out[(size_t)m * 1024 + n] = acc[mi][ni][r] + bb;
            }
        }
    }
}

// ---------------------------------------------------------------------------
// V transpose: Vb[bh][n][64] -> Vt[bh][64][2048]
// ---------------------------------------------------------------------------
__global__ __launch_bounds__(256) void transpose_v(
    const ushort* __restrict__ Vb, ushort* __restrict__ Vt)
{
    const int w = threadIdx.x >> 6;
    const int lane = threadIdx.x & 63;
    const int tile = blockIdx.x * 4 + w;
    const int bh = tile >> 5;
    const int kb = (tile & 31) << 6;

    const ushort* src = Vb + ((size_t)bh * 2048 + kb) * 64 + lane;
    ushort v[64];
    #pragma unroll
    for (int k = 0; k < 64; ++k)
        v[k] = src[(size_t)k * 64];

    ushort* dst = Vt + ((size_t)bh * 64 + lane) * 2048 + kb;
    #pragma unroll
    for (int k = 0; k < 64; k += 8) {
        bf16x8 t;
        #pragma unroll
        for (int j = 0; j < 8; ++j) t[j] = (short)v[k + j];
        *(bf16x8*)(dst + k) = t;
    }
}

// ---------------------------------------------------------------------------
// MFMA flash attention (causal). 1 wave = 16 q-rows, 4 waves/block.
// Output Ob is bf16 [b][n][h*64].
// ---------------------------------------------------------------------------
__global__ __launch_bounds__(256) void flash_mfma(
    const ushort* __restrict__ Qb,
    const ushort* __restrict__ Kb,
    const ushort* __restrict__ Vt,
    ushort* __restrict__ Ob)
{
    __shared__ ushort Ps[4][16][80];

    const int tid = threadIdx.x;
    const int w = tid >> 6;
    const int lane = tid & 63;
    const int l15 = lane & 15;
    const int quad = lane >> 4;

    const int qt = blockIdx.x;
    const int bh = blockIdx.y;
    const int q0 = qt << 6;

    const ushort* qptr = Qb + ((size_t)bh * 2048 + q0 + w * 16 + l15) * 64 + quad * 8;
    bf16x8 qf0 = *(const bf16x8*)qptr;
    bf16x8 qf1 = *(const bf16x8*)(qptr + 32);

    float m_r[4], l_r[4];
    f32x4 o[4];
    #pragma unroll
    for (int r = 0; r < 4; ++r) { m_r[r] = -INFINITY; l_r[r] = 0.f; }
    #pragma unroll
    for (int nb = 0; nb < 4; ++nb) o[nb] = (f32x4){0.f, 0.f, 0.f, 0.f};

    for (int jt = 0; jt <= qt; ++jt) {
        const bool diag = (jt == qt);

        f32x4 S[4];
        const ushort* kbase = Kb + ((size_t)bh * 2048 + (jt << 6)) * 64;
        #pragma unroll
        for (int cb = 0; cb < 4; ++cb) {
            const ushort* kp = kbase + (size_t)(cb * 16 + l15) * 64 + quad * 8;
            bf16x8 kf0 = *(const bf16x8*)kp;
            bf16x8 kf1 = *(const bf16x8*)(kp + 32);
            f32x4 s = (f32x4){0.f, 0.f, 0.f, 0.f};
            s = __builtin_amdgcn_mfma_f32_16x16x32_bf16(qf0, kf0, s, 0, 0, 0);
            s = __builtin_amdgcn_mfma_f32_16x16x32_bf16(qf1, kf1, s, 0, 0, 0);
            S[cb] = s;
        }

        #pragma unroll
        for (int cb = 0; cb < 4; ++cb) {
            const int jg = (jt << 6) + cb * 16 + l15;
            #pragma unroll
            for (int r = 0; r < 4; ++r) {
                float s = S[cb][r] * 0.125f;
                const int ig = q0 + w * 16 + quad * 4 + r;
                if (diag && jg > ig) s = -INFINITY;
                S[cb][r] = s;
            }
        }

        float corr[4];
        #pragma unroll
        for (int r = 0; r < 4; ++r) {
            float mx = fmaxf(fmaxf(S[0][r], S[1][r]), fmaxf(S[2][r], S[3][r]));
            mx = fmaxf(mx, __shfl_xor(mx, 1));
            mx = fmaxf(mx, __shfl_xor(mx, 2));
            mx = fmaxf(mx, __shfl_xor(mx, 4));
            mx = fmaxf(mx, __shfl_xor(mx, 8));
            const float mnew = fmaxf(m_r[r], mx);
            corr[r] = __expf(m_r[r] - mnew);
            float rs = 0.f;
            #pragma unroll
            for (int cb = 0; cb < 4; ++cb) {
                float p = __expf(S[cb][r] - mnew);
                S[cb][r] = p;
                rs += p;
            }
            rs += __shfl_xor(rs, 1);
            rs += __shfl_xor(rs, 2);
            rs += __shfl_xor(rs, 4);
            rs += __shfl_xor(rs, 8);
            l_r[r] = l_r[r] * corr[r] + rs;
            m_r[r] = mnew;
        }

        #pragma unroll
        for (int cb = 0; cb < 4; ++cb)
            #pragma unroll
            for (int r = 0; r < 4; ++r)
                Ps[w][quad * 4 + r][cb * 16 + l15] = f2bf(S[cb][r]);
        #pragma unroll
        for (int nb = 0; nb < 4; ++nb)
            #pragma unroll
            for (int r = 0; r < 4; ++r)
                o[nb][r] *= corr[r];

        bf16x8 pf0 = *(const bf16x8*)&Ps[w][l15][quad * 8];
        bf16x8 pf1 = *(const bf16x8*)&Ps[w][l15][32 + quad * 8];
        const ushort* vtb = Vt + (size_t)bh * 64 * 2048 + (jt << 6);
        #pragma unroll
        for (int nb = 0; nb < 4; ++nb) {
            const ushort* vp = vtb + (size_t)(nb * 16 + l15) * 2048 + quad * 8;
            bf16x8 vf0 = *(const bf16x8*)vp;
            bf16x8 vf1 = *(const bf16x8*)(vp + 32);
            o[nb] = __builtin_amdgcn_mfma_f32_16x16x32_bf16(pf0, vf0, o[nb], 0, 0, 0);
            o[nb] = __builtin_amdgcn_mfma_f32_16x16x32_bf16(pf1, vf1, o[nb], 0, 0, 0);
        }
    }

    const int b = bh >> 4, h = bh & 15;
    #pragma unroll
    for (int r = 0; r < 4; ++r) {
        const int ig = q0 + w * 16 + quad * 4 + r;
        const float inv = 1.f / l_r[r];
        ushort* op = Ob + ((size_t)(b * 2048 + ig)) * 1024 + h * 64 + l15;
        #pragma unroll
        for (int nb = 0; nb < 4; ++nb)
            op[nb * 16] = f2bf(o[nb][r] * inv);
    }
}

// ---------------------------------------------------------------------------
extern "C" void kernel_launch(void* const* d_in, const int* in_sizes, int n_in,
                              void* d_out, int out_size, void* d_ws, size_t ws_size,
                              hipStream_t stream) {
    const float* x   = (const float*)d_in[0];
    const float* Wq  = (const float*)d_in[1];
    const float* Wkv = (const float*)d_in[2];
    const float* Wo  = (const float*)d_in[3];
    const float* bo  = (const float*)d_in[4];
    float* out = (float*)d_out;

    const size_t SEG = (size_t)8388608 * 2;   // 16 MB per bf16 [8192x1024] buffer
    char* ws = (char*)d_ws;
    ushort* xb = (ushort*)(ws);
    ushort* Qb = (ushort*)(ws + SEG);
    ushort* Kb = (ushort*)(ws + SEG * 2);
    ushort* Vb = (ushort*)(ws + SEG * 3);
    ushort* Vt = (ushort*)(ws + SEG * 4);
    ushort* Ob = (ushort*)(ws + SEG * 5);
    ushort* Wt = (ushort*)(ws + SEG * 6);     // [4096][1024] bf16, 8 MB

    convert_x<<<dim3(4096), 256, 0, stream>>>(x, xb);
    prep_w<<<dim3(256), 256, 0, stream>>>(Wq, Wkv, Wo, Wt);
    gemm_qkv<<<dim3(24, 64), 256, 0, stream>>>(xb, Wt, Qb, Kb, Vb);
    transpose_v<<<dim3(512), 256, 0, stream>>>(Vb, Vt);
    flash_mfma<<<dim3(32, 64), 256, 0, stream>>>(Qb, Kb, Vt, Ob);
    gemm_out<<<dim3(8, 64), 256, 0, stream>>>(Ob, Wt + (size_t)3072 * 1024, bo, out);
}

// Round 4
// 381.384 us; speedup vs baseline: 7.4610x; 1.6800x over previous
//
#include <hip/hip_runtime.h>
#include <hip/hip_bf16.h>
#include <math.h>

typedef __attribute__((ext_vector_type(8))) short bf16x8;
typedef __attribute__((ext_vector_type(4))) float f32x4;

static __device__ inline ushort f2bf(float f) {
    union { float f; unsigned u; } v; v.f = f;
    unsigned r = (v.u + 0x7fff + ((v.u >> 16) & 1)) >> 16;   // RNE
    return (ushort)r;
}

#define GLD_LDS(g, l) \
    __builtin_amdgcn_global_load_lds( \
        (const __attribute__((address_space(1))) void*)(g), \
        (__attribute__((address_space(3))) void*)(l), 16, 0, 0)

// ---------------------------------------------------------------------------
// x fp32 -> bf16
// ---------------------------------------------------------------------------
__global__ __launch_bounds__(256) void convert_x(
    const float* __restrict__ x, ushort* __restrict__ xb)
{
    const size_t i = ((size_t)blockIdx.x * 256 + threadIdx.x) * 8;
    float4 a = *(const float4*)(x + i);
    float4 b = *(const float4*)(x + i + 4);
    bf16x8 t;
    t[0] = (short)f2bf(a.x); t[1] = (short)f2bf(a.y);
    t[2] = (short)f2bf(a.z); t[3] = (short)f2bf(a.w);
    t[4] = (short)f2bf(b.x); t[5] = (short)f2bf(b.y);
    t[6] = (short)f2bf(b.z); t[7] = (short)f2bf(b.w);
    *(bf16x8*)(xb + i) = t;
}

// ---------------------------------------------------------------------------
// Weights fp32 [K][N] -> Wt bf16 [4096][1024] transposed
// ---------------------------------------------------------------------------
__global__ __launch_bounds__(256) void prep_w(
    const float* __restrict__ Wq, const float* __restrict__ Wkv,
    const float* __restrict__ Wo, ushort* __restrict__ Wt)
{
    const int w = threadIdx.x >> 6;
    const int lane = threadIdx.x & 63;
    const int tile = blockIdx.x * 4 + w;
    const int r0 = (tile >> 4) << 6;
    const int k0 = (tile & 15) << 6;

    const float* src; int ld, c0;
    if (r0 < 1024)      { src = Wq;  ld = 1024; c0 = r0; }
    else if (r0 < 3072) { src = Wkv; ld = 2048; c0 = r0 - 1024; }
    else                { src = Wo;  ld = 1024; c0 = r0 - 3072; }

    ushort v[64];
    #pragma unroll
    for (int k = 0; k < 64; ++k)
        v[k] = f2bf(src[(size_t)(k0 + k) * ld + c0 + lane]);

    ushort* dst = Wt + (size_t)(r0 + lane) * 1024 + k0;
    #pragma unroll
    for (int k = 0; k < 64; k += 8) {
        bf16x8 t;
        #pragma unroll
        for (int j = 0; j < 8; ++j) t[j] = (short)v[k + j];
        *(bf16x8*)(dst + k) = t;
    }
}

// ---------------------------------------------------------------------------
// m97-style bf16 MFMA GEMM main loop (128x128 tile, BK=32)
// ---------------------------------------------------------------------------
#define GEMM_MAIN_LOOP(Aptr, Btptr)                                            \
    __shared__ ushort As[128 * 32];                                            \
    __shared__ ushort Bs[128 * 32];                                            \
    const int tid = threadIdx.x;                                               \
    const int lane = tid & 63;                                                 \
    const int w = tid >> 6;                                                    \
    const int l15 = lane & 15;                                                 \
    const int quad = lane >> 4;                                                \
    const int wm = w & 1, wn = w >> 1;                                         \
    const int rowBase = blockIdx.y * 128;                                      \
    const int colBase = blockIdx.x * 128;                                      \
    const int sRow = lane >> 2;                                                \
    const int sOff = (lane & 3) * 8;                                           \
    const ushort* aG0 = (Aptr) + (size_t)(rowBase + (w*2+0)*16 + sRow) * 1024 + sOff; \
    const ushort* aG1 = (Aptr) + (size_t)(rowBase + (w*2+1)*16 + sRow) * 1024 + sOff; \
    const ushort* bG0 = (Btptr) + (size_t)(colBase + (w*2+0)*16 + sRow) * 1024 + sOff; \
    const ushort* bG1 = (Btptr) + (size_t)(colBase + (w*2+1)*16 + sRow) * 1024 + sOff; \
    ushort* aL0 = As + (w*2+0)*512;                                            \
    ushort* aL1 = As + (w*2+1)*512;                                            \
    ushort* bL0 = Bs + (w*2+0)*512;                                            \
    ushort* bL1 = Bs + (w*2+1)*512;                                            \
    f32x4 acc[4][4];                                                           \
    _Pragma("unroll")                                                          \
    for (int i = 0; i < 4; ++i)                                                \
        _Pragma("unroll")                                                      \
        for (int j = 0; j < 4; ++j) acc[i][j] = (f32x4){0.f,0.f,0.f,0.f};      \
    for (int k0 = 0; k0 < 1024; k0 += 32) {                                    \
        __syncthreads();                                                       \
        GLD_LDS(aG0 + k0, aL0);                                                \
        GLD_LDS(aG1 + k0, aL1);                                                \
        GLD_LDS(bG0 + k0, bL0);                                                \
        GLD_LDS(bG1 + k0, bL1);                                                \
        __syncthreads();                                                       \
        bf16x8 af[4], bf[4];                                                   \
        _Pragma("unroll")                                                      \
        for (int mi = 0; mi < 4; ++mi)                                         \
            af[mi] = *(const bf16x8*)&As[(wm*64 + mi*16 + l15)*32 + quad*8];   \
        _Pragma("unroll")                                                      \
        for (int ni = 0; ni < 4; ++ni)                                         \
            bf[ni] = *(const bf16x8*)&Bs[(wn*64 + ni*16 + l15)*32 + quad*8];   \
        _Pragma("unroll")                                                      \
        for (int mi = 0; mi < 4; ++mi)                                         \
            _Pragma("unroll")                                                  \
            for (int ni = 0; ni < 4; ++ni)                                     \
                acc[mi][ni] = __builtin_amdgcn_mfma_f32_16x16x32_bf16(         \
                    af[mi], bf[ni], acc[mi][ni], 0, 0, 0);                     \
    }

// ---------------------------------------------------------------------------
// GEMM 1: xb x Wt[0:3072] -> Q (pre-scaled by 1/8), K in [bh][n][64];
//         V directly transposed into Vt [bh*64+d][2048]
// ---------------------------------------------------------------------------
__global__ __launch_bounds__(256) void gemm_qkv(
    const ushort* __restrict__ A, const ushort* __restrict__ Bt,
    ushort* __restrict__ Qb, ushort* __restrict__ Kb, ushort* __restrict__ Vt)
{
    GEMM_MAIN_LOOP(A, Bt)

    const int seg = colBase >> 10;          // 0=Q 1=K 2=V
    if (seg == 2) {
        #pragma unroll
        for (int mi = 0; mi < 4; ++mi) {
            #pragma unroll
            for (int ni = 0; ni < 4; ++ni) {
                const int c = (colBase + wn*64 + ni*16 + l15) & 1023;
                const int h = c >> 6, d = c & 63;
                const int m = rowBase + wm*64 + mi*16 + quad*4;
                const int b = m >> 11, nn = m & 2047;
                ushort4 v;
                v.x = f2bf(acc[mi][ni][0]); v.y = f2bf(acc[mi][ni][1]);
                v.z = f2bf(acc[mi][ni][2]); v.w = f2bf(acc[mi][ni][3]);
                *(ushort4*)(Vt + ((size_t)(b*16 + h)*64 + d)*2048 + nn) = v;
            }
        }
    } else {
        ushort* dst = seg ? Kb : Qb;
        const float sc = seg ? 1.0f : 0.125f;   // fold 1/sqrt(64) into Q
        #pragma unroll
        for (int mi = 0; mi < 4; ++mi) {
            #pragma unroll
            for (int ni = 0; ni < 4; ++ni) {
                const int c = (colBase + wn*64 + ni*16 + l15) & 1023;
                const int h = c >> 6, d = c & 63;
                #pragma unroll
                for (int r = 0; r < 4; ++r) {
                    const int m = rowBase + wm*64 + mi*16 + quad*4 + r;
                    const int b = m >> 11, nn = m & 2047;
                    dst[((((size_t)b*16 + h)*2048 + nn) << 6) + d] = f2bf(acc[mi][ni][r] * sc);
                }
            }
        }
    }
}

// ---------------------------------------------------------------------------
// GEMM 2: Ob x Wt[3072:4096] + bo -> fp32 out
// ---------------------------------------------------------------------------
__global__ __launch_bounds__(256) void gemm_out(
    const ushort* __restrict__ A, const ushort* __restrict__ Bt,
    const float* __restrict__ bo, float* __restrict__ out)
{
    GEMM_MAIN_LOOP(A, Bt)

    #pragma unroll
    for (int mi = 0; mi < 4; ++mi) {
        #pragma unroll
        for (int ni = 0; ni < 4; ++ni) {
            const int n = colBase + wn*64 + ni*16 + l15;
            const float bb = bo[n];
            #pragma unroll
            for (int r = 0; r < 4; ++r) {
                const int m = rowBase + wm*64 + mi*16 + quad*4 + r;
                out[(size_t)m * 1024 + n] = acc[mi][ni][r] + bb;
            }
        }
    }
}

// ---------------------------------------------------------------------------
// MFMA flash attention. Block = 4 waves x 32 q-rows = 128-row q-tile.
// K/V 64-key tiles staged in LDS (xor-swizzled) via global_load_lds.
// Q pre-scaled. Vt is [bh*64+d][2048].
// ---------------------------------------------------------------------------
__device__ inline bf16x8 lds_frag(const ushort* S, int row, int chunk) {
    return *(const bf16x8*)(S + row * 64 + (((chunk ^ (row & 7))) << 3));
}

__global__ __launch_bounds__(256, 4) void flash_mfma(
    const ushort* __restrict__ Qb,
    const ushort* __restrict__ Kb,
    const ushort* __restrict__ Vt,
    ushort* __restrict__ Ob)
{
    __shared__ ushort Ks[64 * 64];
    __shared__ ushort Vs[64 * 64];
    __shared__ ushort Ps[4][32][72];

    const int tid = threadIdx.x;
    const int w = tid >> 6;
    const int lane = tid & 63;
    const int l15 = lane & 15;
    const int quad = lane >> 4;

    // XCD swizzle: blk%8 = xcd slot, 8 bh per slot (4MB K+V fits one L2);
    // qt descending so long blocks dispatch first.
    const int blk = blockIdx.x;
    const int bh = (blk & 7) * 8 + (blk >> 7);
    const int qt = 15 - ((blk >> 3) & 15);
    const int q0 = qt << 7;

    // staging: 512 16B chunks per tile, 2 per thread, xor-swizzled
    const int r0 = tid >> 3, r1 = r0 + 32;
    const int cg0 = (tid & 7) ^ (r0 & 7);
    const int cg1 = (tid & 7) ^ (r1 & 7);
    const ushort* kg0 = Kb + (size_t)bh * 131072 + r0 * 64 + cg0 * 8;
    const ushort* kg1 = Kb + (size_t)bh * 131072 + r1 * 64 + cg1 * 8;
    const ushort* vg0 = Vt + ((size_t)bh * 64 + r0) * 2048 + cg0 * 8;
    const ushort* vg1 = Vt + ((size_t)bh * 64 + r1) * 2048 + cg1 * 8;
    ushort* kl0 = Ks + tid * 8;
    ushort* kl1 = kl0 + 2048;
    ushort* vl0 = Vs + tid * 8;
    ushort* vl1 = vl0 + 2048;

    // Q fragments for this wave's 32 rows (2 m-tiles), pre-scaled in gemm_qkv
    const int rb0 = q0 + w * 32;
    bf16x8 qf[2][2];
    #pragma unroll
    for (int mi = 0; mi < 2; ++mi) {
        const ushort* qp = Qb + ((size_t)bh * 2048 + rb0 + mi*16 + l15) * 64 + quad * 8;
        qf[mi][0] = *(const bf16x8*)qp;
        qf[mi][1] = *(const bf16x8*)(qp + 32);
    }

    float m_r[2][4], l_r[2][4];
    f32x4 o[2][4];
    #pragma unroll
    for (int mi = 0; mi < 2; ++mi)
        #pragma unroll
        for (int r = 0; r < 4; ++r) { m_r[mi][r] = -INFINITY; l_r[mi][r] = 0.f; }
    #pragma unroll
    for (int mi = 0; mi < 2; ++mi)
        #pragma unroll
        for (int nb = 0; nb < 4; ++nb) o[mi][nb] = (f32x4){0.f, 0.f, 0.f, 0.f};

    const int jmax = 2 * qt + 1;
    for (int jt = 0; jt <= jmax; ++jt) {
        __syncthreads();
        GLD_LDS(kg0, kl0); GLD_LDS(kg1, kl1);
        GLD_LDS(vg0, vl0); GLD_LDS(vg1, vl1);
        __syncthreads();
        kg0 += 4096; kg1 += 4096; vg0 += 64; vg1 += 64;

        const int j0 = jt << 6;
        if (j0 <= rb0 + 31) {
            // which m-tiles are active (all keys <= all rows check via multiples)
            const bool act0 = (j0 <= rb0);
            const bool act1 = (j0 <= rb0 + 16);

            // ---- S = Q K^T ----
            f32x4 S[2][4];
            #pragma unroll
            for (int cb = 0; cb < 4; ++cb) {
                const int R = cb * 16 + l15;
                bf16x8 kf0 = lds_frag(Ks, R, quad);
                bf16x8 kf1 = lds_frag(Ks, R, quad + 4);
                #pragma unroll
                for (int mi = 0; mi < 2; ++mi) {
                    f32x4 s = (f32x4){0.f, 0.f, 0.f, 0.f};
                    s = __builtin_amdgcn_mfma_f32_16x16x32_bf16(qf[mi][0], kf0, s, 0, 0, 0);
                    s = __builtin_amdgcn_mfma_f32_16x16x32_bf16(qf[mi][1], kf1, s, 0, 0, 0);
                    S[mi][cb] = s;
                }
            }

            #pragma unroll
            for (int mi = 0; mi < 2; ++mi) {
                if (!(mi ? act1 : act0)) continue;
                const int rbase = rb0 + mi * 16;
                // causal mask (only near-diagonal tiles need it)
                if (j0 + 63 > rbase) {
                    #pragma unroll
                    for (int cb = 0; cb < 4; ++cb) {
                        const int jg = j0 + cb * 16 + l15;
                        #pragma unroll
                        for (int r = 0; r < 4; ++r) {
                            const int ig = rbase + quad * 4 + r;
                            if (jg > ig) S[mi][cb][r] = -INFINITY;
                        }
                    }
                }
                // online softmax
                #pragma unroll
                for (int r = 0; r < 4; ++r) {
                    float mx = fmaxf(fmaxf(S[mi][0][r], S[mi][1][r]),
                                     fmaxf(S[mi][2][r], S[mi][3][r]));
                    mx = fmaxf(mx, __shfl_xor(mx, 1));
                    mx = fmaxf(mx, __shfl_xor(mx, 2));
                    mx = fmaxf(mx, __shfl_xor(mx, 4));
                    mx = fmaxf(mx, __shfl_xor(mx, 8));
                    const float mnew = fmaxf(m_r[mi][r], mx);
                    const float corr = __expf(m_r[mi][r] - mnew);
                    float rs = 0.f;
                    #pragma unroll
                    for (int cb = 0; cb < 4; ++cb) {
                        float p = __expf(S[mi][cb][r] - mnew);
                        S[mi][cb][r] = p;
                        rs += p;
                    }
                    rs += __shfl_xor(rs, 1);
                    rs += __shfl_xor(rs, 2);
                    rs += __shfl_xor(rs, 4);
                    rs += __shfl_xor(rs, 8);
                    l_r[mi][r] = l_r[mi][r] * corr + rs;
                    m_r[mi][r] = mnew;
                    #pragma unroll
                    for (int nb = 0; nb < 4; ++nb) o[mi][nb][r] *= corr;
                }
                // P -> per-wave LDS (A-operand layout transform)
                #pragma unroll
                for (int cb = 0; cb < 4; ++cb)
                    #pragma unroll
                    for (int r = 0; r < 4; ++r)
                        Ps[w][mi*16 + quad*4 + r][cb*16 + l15] = f2bf(S[mi][cb][r]);
            }

            // ---- O += P V ----
            bf16x8 pf[2][2];
            #pragma unroll
            for (int mi = 0; mi < 2; ++mi) {
                pf[mi][0] = *(const bf16x8*)&Ps[w][mi*16 + l15][quad * 8];
                pf[mi][1] = *(const bf16x8*)&Ps[w][mi*16 + l15][32 + quad * 8];
            }
            #pragma unroll
            for (int nb = 0; nb < 4; ++nb) {
                const int R = nb * 16 + l15;
                bf16x8 vf0 = lds_frag(Vs, R, quad);
                bf16x8 vf1 = lds_frag(Vs, R, quad + 4);
                if (act0) {
                    o[0][nb] = __builtin_amdgcn_mfma_f32_16x16x32_bf16(pf[0][0], vf0, o[0][nb], 0, 0, 0);
                    o[0][nb] = __builtin_amdgcn_mfma_f32_16x16x32_bf16(pf[0][1], vf1, o[0][nb], 0, 0, 0);
                }
                if (act1) {
                    o[1][nb] = __builtin_amdgcn_mfma_f32_16x16x32_bf16(pf[1][0], vf0, o[1][nb], 0, 0, 0);
                    o[1][nb] = __builtin_amdgcn_mfma_f32_16x16x32_bf16(pf[1][1], vf1, o[1][nb], 0, 0, 0);
                }
            }
        }
    }

    // ---- normalize + store O bf16 [b][n][h*64] ----
    const int b = bh >> 4, h = bh & 15;
    #pragma unroll
    for (int mi = 0; mi < 2; ++mi) {
        #pragma unroll
        for (int r = 0; r < 4; ++r) {
            const int ig = rb0 + mi*16 + quad*4 + r;
            const float inv = 1.f / l_r[mi][r];
            ushort* op = Ob + ((size_t)(b * 2048 + ig)) * 1024 + h * 64 + l15;
            #pragma unroll
            for (int nb = 0; nb < 4; ++nb)
                op[nb * 16] = f2bf(o[mi][nb][r] * inv);
        }
    }
}

// ---------------------------------------------------------------------------
extern "C" void kernel_launch(void* const* d_in, const int* in_sizes, int n_in,
                              void* d_out, int out_size, void* d_ws, size_t ws_size,
                              hipStream_t stream) {
    const float* x   = (const float*)d_in[0];
    const float* Wq  = (const float*)d_in[1];
    const float* Wkv = (const float*)d_in[2];
    const float* Wo  = (const float*)d_in[3];
    const float* bo  = (const float*)d_in[4];
    float* out = (float*)d_out;

    const size_t SEG = (size_t)8388608 * 2;   // 16 MB per bf16 [8192x1024]
    char* ws = (char*)d_ws;
    ushort* xb = (ushort*)(ws);
    ushort* Qb = (ushort*)(ws + SEG);
    ushort* Kb = (ushort*)(ws + SEG * 2);
    ushort* Vt = (ushort*)(ws + SEG * 3);     // [bh*64+d][2048]
    ushort* Ob = (ushort*)(ws + SEG * 4);
    ushort* Wt = (ushort*)(ws + SEG * 5);     // [4096][1024] bf16

    convert_x<<<dim3(4096), 256, 0, stream>>>(x, xb);
    prep_w<<<dim3(256), 256, 0, stream>>>(Wq, Wkv, Wo, Wt);
    gemm_qkv<<<dim3(24, 64), 256, 0, stream>>>(xb, Wt, Qb, Kb, Vt);
    flash_mfma<<<dim3(1024), 256, 0, stream>>>(Qb, Kb, Vt, Ob);
    gemm_out<<<dim3(8, 64), 256, 0, stream>>>(Ob, Wt + (size_t)3072 * 1024, bo, out);
}